// Round 3
// baseline (263.196 us; speedup 1.0000x reference)
//
#include <hip/hip_runtime.h>
#include <math.h>

// Problem constants (B, SK, SQ, H, D, N) = (4, 4096, 4096, 16, 64, 32)
#define SK 4096
#define SQ 4096
#define HH 16
#define DD 64
#define NN 32
#define KBATCH 64           // keys staged per LDS batch

// freqs[n] = (n / (N-1)) * N * pi
__device__ __forceinline__ float freq_of(int n) {
    return (float)n * (32.0f * (float)M_PI / 31.0f);
}

// ---------------------------------------------------------------------------
// Kernel 1: partial C/S sums.  C[n,d] = sum_k cos(f_n * key_k) * v[k,d],
// S likewise with sin.  Grid: 64 (b,h) pairs x NC K-chunks.
// Thread layout: d4 = tid&15 (4 consecutive d via float4), ng = tid>>4 (2 n's).
// sincos staged in LDS per 64-key batch; trig read as one ds_read_b128.
// Inner loop: explicit 4-deep register prefetch (next 4 keys load while
// current 4 keys' 64 FMAs issue) -> 4 dwordx4 in flight per wave.
// __launch_bounds__(256,4): <=128 VGPR so the pipeline actually fits
// (round-2's (256,8) forced VGPR=32 and serialized the loads).
// Partial layout: P[chunk][bh][cs][n][d]  (cs: 0=C, 1=S)
// ---------------------------------------------------------------------------
template <int NC>
__global__ __launch_bounds__(256, 4) void k1_partial(
    const float* __restrict__ key_in, const float* __restrict__ value,
    float* __restrict__ P)
{
    const int KPC = SK / NC;
    const int chunk = blockIdx.x & (NC - 1);
    const int bh    = blockIdx.x / NC;
    const int b = bh >> 4, h = bh & 15;
    const int tid = threadIdx.x;
    const int d4 = tid & 15, ng = tid >> 4;
    const int d0 = d4 * 4, n0 = ng * 2;

    __shared__ float2 csK[KBATCH][NN];   // 16 KB: (cos, sin) per (key, n)

    float accC0[4] = {0,0,0,0}, accS0[4] = {0,0,0,0};
    float accC1[4] = {0,0,0,0}, accS1[4] = {0,0,0,0};

    for (int bb = 0; bb < KPC / KBATCH; ++bb) {
        const int kbase = chunk * KPC + bb * KBATCH;
        // --- stage sincos for this key batch (KBATCH*NN = 2048 pairs) ---
        #pragma unroll
        for (int i = 0; i < (KBATCH * NN) / 256; ++i) {  // 8 per thread
            int idx = tid + i * 256;
            int kl = idx >> 5, n = idx & 31;
            float kv = key_in[(size_t)(b * SK + kbase + kl) * HH + h];
            float s, c;
            __sincosf(freq_of(n) * kv, &s, &c);
            csK[kl][n] = make_float2(c, s);
        }
        __syncthreads();

        const float* vbase = value + (size_t)(b * SK + kbase) * (HH * DD) + h * DD + d0;
        // 4-deep prefetch pipeline over 16 groups of 4 keys
        float4 vb[4];
        #pragma unroll
        for (int j = 0; j < 4; ++j)
            vb[j] = *(const float4*)(vbase + (size_t)j * (HH * DD));

        #pragma unroll
        for (int g = 0; g < KBATCH / 4; ++g) {
            float4 vn[4];
            if (g + 1 < KBATCH / 4) {           // folds away: g is compile-time
                #pragma unroll
                for (int j = 0; j < 4; ++j)
                    vn[j] = *(const float4*)(vbase + (size_t)((g + 1) * 4 + j) * (HH * DD));
            }
            #pragma unroll
            for (int j = 0; j < 4; ++j) {
                const int kl = g * 4 + j;
                // one ds_read_b128: (cos0,sin0,cos1,sin1); banks 0-15, no conflict
                float4 cs = *(const float4*)&csK[kl][n0];
                float4 v = vb[j];
                accC0[0] += cs.x * v.x; accC0[1] += cs.x * v.y;
                accC0[2] += cs.x * v.z; accC0[3] += cs.x * v.w;
                accS0[0] += cs.y * v.x; accS0[1] += cs.y * v.y;
                accS0[2] += cs.y * v.z; accS0[3] += cs.y * v.w;
                accC1[0] += cs.z * v.x; accC1[1] += cs.z * v.y;
                accC1[2] += cs.z * v.z; accC1[3] += cs.z * v.w;
                accS1[0] += cs.w * v.x; accS1[1] += cs.w * v.y;
                accS1[2] += cs.w * v.z; accS1[3] += cs.w * v.w;
            }
            if (g + 1 < KBATCH / 4) {
                #pragma unroll
                for (int j = 0; j < 4; ++j) vb[j] = vn[j];
            }
        }
        __syncthreads();
    }

    // write partials
    float* Pb = P + ((size_t)chunk * 64 + bh) * (2 * NN * DD);
    *(float4*)(Pb + (size_t)n0 * DD + d0)              = make_float4(accC0[0], accC0[1], accC0[2], accC0[3]);
    *(float4*)(Pb + (size_t)(n0 + 1) * DD + d0)        = make_float4(accC1[0], accC1[1], accC1[2], accC1[3]);
    *(float4*)(Pb + 2048 + (size_t)n0 * DD + d0)       = make_float4(accS0[0], accS0[1], accS0[2], accS0[3]);
    *(float4*)(Pb + 2048 + (size_t)(n0 + 1) * DD + d0) = make_float4(accS1[0], accS1[1], accS1[2], accS1[3]);
}

// ---------------------------------------------------------------------------
// Kernel 1b: reduce the NC chunk partials.  CS[bh][cs][n][d] (262144 floats).
// ---------------------------------------------------------------------------
template <int NC>
__global__ __launch_bounds__(256) void k1_reduce(
    const float* __restrict__ P, float* __restrict__ CS)
{
    int gid = blockIdx.x * 256 + threadIdx.x;  // 0 .. 262143
    float acc = 0.f;
    #pragma unroll
    for (int c = 0; c < NC; ++c)
        acc += P[(size_t)c * (64 * 2 * NN * DD) + gid];
    CS[gid] = acc;
}

// ---------------------------------------------------------------------------
// Kernel 2: out[q,d] = sum_n A[q,n]*C[n,d] + B[q,n]*S[n,d]
// A = ra*cos(f_n q) + ia*sin(f_n q);  B = ra*sin(f_n q) - ia*cos(f_n q)
// Grid: 2048 blocks = 64 (b,h) x 32 q-chunks of 128 queries.
// Thread: d4 = tid&15 (4 d), qg = tid>>4 (8 q) -> 8x4 register tile.
// A/B stored n-paired as float4 with column swizzle col=(n2+qg)&15 so the
// 4 distinct addresses per wave hit distinct banks (conflict-free).
// ---------------------------------------------------------------------------
__global__ __launch_bounds__(256) void k2_out(
    const float* __restrict__ query, const float* __restrict__ ramps,
    const float* __restrict__ iamps, const float* __restrict__ CS,
    float* __restrict__ out)
{
    const int bh = blockIdx.x >> 5;
    const int qc = blockIdx.x & 31;
    const int b = bh >> 4, h = bh & 15;
    const int qbase = qc * 128;
    const int tid = threadIdx.x;

    __shared__ float  csC[NN][DD];        // 8 KB  (C plane)
    __shared__ float  csS[NN][DD];        // 8 KB  (S plane)
    __shared__ float4 abQ[128][16];       // 32 KB: (A_n,B_n,A_n1,B_n1) swizzled

    // load C/S planes (each 2048 floats), coalesced
    const float* CSb = CS + (size_t)bh * (2 * NN * DD);
    #pragma unroll
    for (int i = 0; i < 8; ++i) {
        int idx = tid + i * 256;
        ((float*)csC)[idx] = CSb[idx];
        ((float*)csS)[idx] = CSb[2048 + idx];
    }
    // stage A/B for 128 queries x 32 n  (16 sincos per thread)
    #pragma unroll
    for (int i = 0; i < 16; ++i) {
        int idx = tid + i * 256;
        int ql = idx >> 5, n = idx & 31;
        float qv = query[(size_t)(b * SQ + qbase + ql) * HH + h];
        float ra = ramps[h * NN + n], ia = iamps[h * NN + n];
        float s, c;
        __sincosf(freq_of(n) * qv, &s, &c);
        int col = ((n >> 1) + (ql >> 3)) & 15;
        ((float2*)&abQ[ql][col])[n & 1] = make_float2(ra * c + ia * s, ra * s - ia * c);
    }
    __syncthreads();

    const int d4 = tid & 15, qg = tid >> 4;   // qg: 0..15, owns 8 queries
    const int d0 = d4 * 4;
    float acc[8][4];
    #pragma unroll
    for (int qi = 0; qi < 8; ++qi)
        #pragma unroll
        for (int dj = 0; dj < 4; ++dj) acc[qi][dj] = 0.f;

    #pragma unroll 4
    for (int n2 = 0; n2 < 16; ++n2) {
        const int n = n2 * 2;
        float4 c0 = *(const float4*)&csC[n][d0];
        float4 s0 = *(const float4*)&csS[n][d0];
        float4 c1 = *(const float4*)&csC[n + 1][d0];
        float4 s1 = *(const float4*)&csS[n + 1][d0];
        const int col = (n2 + qg) & 15;
        #pragma unroll
        for (int qi = 0; qi < 8; ++qi) {
            float4 ab = abQ[qg * 8 + qi][col];  // (A_n, B_n, A_n1, B_n1)
            acc[qi][0] += ab.x * c0.x + ab.y * s0.x + ab.z * c1.x + ab.w * s1.x;
            acc[qi][1] += ab.x * c0.y + ab.y * s0.y + ab.z * c1.y + ab.w * s1.y;
            acc[qi][2] += ab.x * c0.z + ab.y * s0.z + ab.z * c1.z + ab.w * s1.z;
            acc[qi][3] += ab.x * c0.w + ab.y * s0.w + ab.z * c1.w + ab.w * s1.w;
        }
    }

    float* ob = out + (size_t)(b * SQ + qbase) * (HH * DD) + h * DD + d0;
    #pragma unroll
    for (int qi = 0; qi < 8; ++qi) {
        int q = qg * 8 + qi;
        *(float4*)(ob + (size_t)q * (HH * DD)) =
            make_float4(acc[qi][0], acc[qi][1], acc[qi][2], acc[qi][3]);
    }
}

extern "C" void kernel_launch(void* const* d_in, const int* in_sizes, int n_in,
                              void* d_out, int out_size, void* d_ws, size_t ws_size,
                              hipStream_t stream) {
    const float* key_in = (const float*)d_in[0];
    const float* value  = (const float*)d_in[1];
    const float* query  = (const float*)d_in[2];
    const float* ramps  = (const float*)d_in[3];
    const float* iamps  = (const float*)d_in[4];
    float* out = (float*)d_out;

    const size_t CS_FLOATS = 64 * 2 * NN * DD;               // 262144
    const size_t P16_FLOATS = (size_t)16 * CS_FLOATS;        // 16 MB
    const size_t need16 = (P16_FLOATS + CS_FLOATS) * sizeof(float);

    float* P = (float*)d_ws;

    if (ws_size >= need16) {
        // 1024 blocks = 4 blocks/CU; 4-deep prefetch per wave hides latency
        float* CS = P + P16_FLOATS;
        hipLaunchKernelGGL((k1_partial<16>), dim3(64 * 16), dim3(256), 0, stream,
                           key_in, value, P);
        hipLaunchKernelGGL((k1_reduce<16>), dim3(CS_FLOATS / 256), dim3(256), 0, stream,
                           P, CS);
        hipLaunchKernelGGL(k2_out, dim3(64 * 32), dim3(256), 0, stream,
                           query, ramps, iamps, CS, out);
    } else {
        // fallback: 9 MB footprint
        float* CS = P + (size_t)8 * CS_FLOATS;
        hipLaunchKernelGGL((k1_partial<8>), dim3(64 * 8), dim3(256), 0, stream,
                           key_in, value, P);
        hipLaunchKernelGGL((k1_reduce<8>), dim3(CS_FLOATS / 256), dim3(256), 0, stream,
                           P, CS);
        hipLaunchKernelGGL(k2_out, dim3(64 * 32), dim3(256), 0, stream,
                           query, ramps, iamps, CS, out);
    }
}

// Round 4
// 179.186 us; speedup vs baseline: 1.4688x; 1.4688x over previous
//
#include <hip/hip_runtime.h>
#include <math.h>

// Problem constants (B, SK, SQ, H, D, N) = (4, 4096, 4096, 16, 64, 32)
#define SK 4096
#define SQ 4096
#define HH 16
#define DD 64
#define NN 32
#define KB 32               // keys per staged batch in k1

// freqs[n] = (n / (N-1)) * N * pi
__device__ __forceinline__ float freq_of(int n) {
    return (float)n * (32.0f * (float)M_PI / 31.0f);
}

// async global->LDS, 16 B per lane: writes lds_base + lane*16
__device__ __forceinline__ void async16(const float* g, float* l) {
    __builtin_amdgcn_global_load_lds(
        (const __attribute__((address_space(1))) unsigned int*)g,
        (__attribute__((address_space(3))) unsigned int*)l, 16, 0, 0);
}

// ---------------------------------------------------------------------------
// Kernel 1: partial C/S sums.  C[n,d] = sum_k cos(f_n * key_k) * v[k,d],
// S likewise with sin.  Grid: 64 (b,h) x NC K-chunks.
// Double-buffered DMA staging (global_load_lds width=16): value tile
// (32 keys x 64 d = 8 KB) + key rows (2 KB) per batch; ONE barrier per
// batch; DMA for batch bb+1 issued right after the barrier so it flies
// over batch bb's ~1100 cy of compute (no VGPRs involved -> the compiler
// cannot serialize it).  LDS 36 KB -> 4 blocks/CU.
// Thread layout: d4 = tid&15 (4 d), ng = tid>>4 (2 n).
// Partial layout: P[chunk][bh][cs][n][d]  (cs: 0=C, 1=S)
// ---------------------------------------------------------------------------
template <int NC>
__global__ __launch_bounds__(256) void k1_partial(
    const float* __restrict__ key_in, const float* __restrict__ value,
    float* __restrict__ P)
{
    const int KPC = SK / NC;          // keys per chunk
    const int NBATCH = KPC / KB;
    const int chunk = blockIdx.x & (NC - 1);
    const int bh    = blockIdx.x / NC;
    const int b = bh >> 4, h = bh & 15;
    const int tid = threadIdx.x;
    const int w = tid >> 6, lane = tid & 63;
    const int d4 = tid & 15, ng = tid >> 4;
    const int d0 = d4 * 4, n0 = ng * 2;

    __shared__ float  vt[2][KB * DD];     // 16 KB: value tiles
    __shared__ float2 csK[2][KB][NN];     // 16 KB: (cos,sin)
    __shared__ float  kt[2][KB][HH];      //  4 KB: raw key rows

    const int kchunk0 = chunk * KPC;

    // DMA issue for one batch into buffer p (value: 2 issues/wave; keys: wave 0)
    auto issue = [&](int kbase, int p) {
        const float* gv = value + (size_t)(b * SK + kbase + w * 8 + (lane >> 4)) * (HH * DD)
                        + h * DD + (lane & 15) * 4;
        async16(gv,                      &vt[p][w * 512]);
        async16(gv + 4 * (HH * DD),      &vt[p][w * 512 + 256]);
        if (w == 0) {
            const float* gk = key_in + (size_t)(b * SK + kbase) * HH + lane * 4;
            async16(gk,       &kt[p][0][0]);
            async16(gk + 256, &kt[p][0][0] + 256);
        }
    };

    float accC0[4] = {0,0,0,0}, accS0[4] = {0,0,0,0};
    float accC1[4] = {0,0,0,0}, accS1[4] = {0,0,0,0};

    issue(kchunk0, 0);   // prologue: batch 0 in flight

    for (int bb = 0; bb < NBATCH; ++bb) {
        const int p = bb & 1;

        __syncthreads();   // drains DMA for batch bb; csK[p^1] safe to reuse

        if (bb + 1 < NBATCH) issue(kchunk0 + (bb + 1) * KB, p ^ 1);

        // sincos for batch bb from the just-landed key rows (n = tid&31 fixed)
        {
            const int n = tid & 31;
            const float fn = freq_of(n);
            #pragma unroll
            for (int i = 0; i < (KB * NN) / 256; ++i) {   // 4 per thread
                int kl = (tid >> 5) + i * 8;
                float s, c;
                __sincosf(fn * kt[p][kl][h], &s, &c);
                csK[p][kl][n] = make_float2(c, s);
            }
        }
        __syncthreads();   // csK[p] visible; vt[p] already landed at prior barrier

        #pragma unroll
        for (int kl = 0; kl < KB; ++kl) {
            float4 cs = *(const float4*)&csK[p][kl][n0];   // (c0,s0,c1,s1)
            float4 v  = *(const float4*)&vt[p][kl * DD + d0];
            accC0[0] += cs.x * v.x; accC0[1] += cs.x * v.y;
            accC0[2] += cs.x * v.z; accC0[3] += cs.x * v.w;
            accS0[0] += cs.y * v.x; accS0[1] += cs.y * v.y;
            accS0[2] += cs.y * v.z; accS0[3] += cs.y * v.w;
            accC1[0] += cs.z * v.x; accC1[1] += cs.z * v.y;
            accC1[2] += cs.z * v.z; accC1[3] += cs.z * v.w;
            accS1[0] += cs.w * v.x; accS1[1] += cs.w * v.y;
            accS1[2] += cs.w * v.z; accS1[3] += cs.w * v.w;
        }
        // no trailing barrier: next iteration writes the OTHER buffers, and
        // the next barrier orders vt[p] reuse behind everyone's compute.
    }

    float* Pb = P + ((size_t)chunk * 64 + bh) * (2 * NN * DD);
    *(float4*)(Pb + (size_t)n0 * DD + d0)              = make_float4(accC0[0], accC0[1], accC0[2], accC0[3]);
    *(float4*)(Pb + (size_t)(n0 + 1) * DD + d0)        = make_float4(accC1[0], accC1[1], accC1[2], accC1[3]);
    *(float4*)(Pb + 2048 + (size_t)n0 * DD + d0)       = make_float4(accS0[0], accS0[1], accS0[2], accS0[3]);
    *(float4*)(Pb + 2048 + (size_t)(n0 + 1) * DD + d0) = make_float4(accS1[0], accS1[1], accS1[2], accS1[3]);
}

// ---------------------------------------------------------------------------
// Kernel 1b: reduce the NC chunk partials.  CS[bh][cs][n][d] (262144 floats).
// ---------------------------------------------------------------------------
template <int NC>
__global__ __launch_bounds__(256) void k1_reduce(
    const float* __restrict__ P, float* __restrict__ CS)
{
    int gid = blockIdx.x * 256 + threadIdx.x;
    float acc = 0.f;
    #pragma unroll
    for (int c = 0; c < NC; ++c)
        acc += P[(size_t)c * (64 * 2 * NN * DD) + gid];
    CS[gid] = acc;
}

// ---------------------------------------------------------------------------
// Kernel 2: out[q,d] = sum_n A[q,n]*C[n,d] + B[q,n]*S[n,d]
// A = ra*cos(f_n q) + ia*sin(f_n q);  B = ra*sin(f_n q) - ia*cos(f_n q)
// Grid: 2048 = 64 (b,h) x 32 q-chunks of 128.  CS tile (16 KB) arrives via
// global_load_lds DMA; query row staged through LDS (was 16 strided global
// loads per thread); ra/ia hoisted (n = tid&31 is constant per thread).
// Compute: 8q x 4d register tile; abQ float4 with col=(n2+qg)&15 swizzle.
// ---------------------------------------------------------------------------
__global__ __launch_bounds__(256) void k2_out(
    const float* __restrict__ query, const float* __restrict__ ramps,
    const float* __restrict__ iamps, const float* __restrict__ CS,
    float* __restrict__ out)
{
    const int bh = blockIdx.x >> 5;
    const int qc = blockIdx.x & 31;
    const int b = bh >> 4, h = bh & 15;
    const int qbase = qc * 128;
    const int tid = threadIdx.x;
    const int w = tid >> 6, lane = tid & 63;

    __shared__ float  csT[2 * NN * DD];   // 16 KB: [0..2047]=C, [2048..]=S
    __shared__ float  qvL[128];
    __shared__ float4 abQ[128][16];       // 32 KB swizzled (A_n,B_n,A_n1,B_n1)

    // DMA the CS tile (contiguous 16 KB), 4 issues per wave
    {
        const float* gcs = CS + (size_t)bh * (2 * NN * DD) + w * 1024 + lane * 4;
        #pragma unroll
        for (int i = 0; i < 4; ++i)
            async16(gcs + i * 256, &csT[w * 1024 + i * 256]);
    }
    if (tid < 128)
        qvL[tid] = query[(size_t)(b * SQ + qbase + tid) * HH + h];
    __syncthreads();   // drains DMA + qvL

    // stage A/B: 16 sincos per thread, n fixed per thread
    {
        const int n = tid & 31;
        const float fn = freq_of(n);
        const float ra = ramps[h * NN + n], ia = iamps[h * NN + n];
        #pragma unroll
        for (int i = 0; i < 16; ++i) {
            int ql = (tid >> 5) + i * 8;
            float s, c;
            __sincosf(fn * qvL[ql], &s, &c);
            int col = ((n >> 1) + (ql >> 3)) & 15;
            ((float2*)&abQ[ql][col])[n & 1] =
                make_float2(ra * c + ia * s, ra * s - ia * c);
        }
    }
    __syncthreads();

    const int d4 = tid & 15, qg = tid >> 4;   // qg 0..15 owns 8 queries
    const int d0 = d4 * 4;
    float acc[8][4];
    #pragma unroll
    for (int qi = 0; qi < 8; ++qi)
        #pragma unroll
        for (int dj = 0; dj < 4; ++dj) acc[qi][dj] = 0.f;

    #pragma unroll 4
    for (int n2 = 0; n2 < 16; ++n2) {
        const int n = n2 * 2;
        float4 c0 = *(const float4*)&csT[n * DD + d0];
        float4 s0 = *(const float4*)&csT[2048 + n * DD + d0];
        float4 c1 = *(const float4*)&csT[(n + 1) * DD + d0];
        float4 s1 = *(const float4*)&csT[2048 + (n + 1) * DD + d0];
        const int col = (n2 + qg) & 15;
        #pragma unroll
        for (int qi = 0; qi < 8; ++qi) {
            float4 ab = abQ[qg * 8 + qi][col];  // (A_n, B_n, A_n1, B_n1)
            acc[qi][0] += ab.x * c0.x + ab.y * s0.x + ab.z * c1.x + ab.w * s1.x;
            acc[qi][1] += ab.x * c0.y + ab.y * s0.y + ab.z * c1.y + ab.w * s1.y;
            acc[qi][2] += ab.x * c0.z + ab.y * s0.z + ab.z * c1.z + ab.w * s1.z;
            acc[qi][3] += ab.x * c0.w + ab.y * s0.w + ab.z * c1.w + ab.w * s1.w;
        }
    }

    float* ob = out + (size_t)(b * SQ + qbase) * (HH * DD) + h * DD + d0;
    #pragma unroll
    for (int qi = 0; qi < 8; ++qi) {
        int q = qg * 8 + qi;
        *(float4*)(ob + (size_t)q * (HH * DD)) =
            make_float4(acc[qi][0], acc[qi][1], acc[qi][2], acc[qi][3]);
    }
}

extern "C" void kernel_launch(void* const* d_in, const int* in_sizes, int n_in,
                              void* d_out, int out_size, void* d_ws, size_t ws_size,
                              hipStream_t stream) {
    const float* key_in = (const float*)d_in[0];
    const float* value  = (const float*)d_in[1];
    const float* query  = (const float*)d_in[2];
    const float* ramps  = (const float*)d_in[3];
    const float* iamps  = (const float*)d_in[4];
    float* out = (float*)d_out;

    const size_t CS_FLOATS = 64 * 2 * NN * DD;               // 262144
    const size_t P16_FLOATS = (size_t)16 * CS_FLOATS;        // 16 MB
    const size_t need16 = (P16_FLOATS + CS_FLOATS) * sizeof(float);

    float* P = (float*)d_ws;

    if (ws_size >= need16) {
        // 1024 blocks = 4 blocks/CU (LDS 36 KB), DMA-pipelined
        float* CS = P + P16_FLOATS;
        hipLaunchKernelGGL((k1_partial<16>), dim3(64 * 16), dim3(256), 0, stream,
                           key_in, value, P);
        hipLaunchKernelGGL((k1_reduce<16>), dim3(CS_FLOATS / 256), dim3(256), 0, stream,
                           P, CS);
        hipLaunchKernelGGL(k2_out, dim3(64 * 32), dim3(256), 0, stream,
                           query, ramps, iamps, CS, out);
    } else {
        float* CS = P + (size_t)8 * CS_FLOATS;
        hipLaunchKernelGGL((k1_partial<8>), dim3(64 * 8), dim3(256), 0, stream,
                           key_in, value, P);
        hipLaunchKernelGGL((k1_reduce<8>), dim3(CS_FLOATS / 256), dim3(256), 0, stream,
                           P, CS);
        hipLaunchKernelGGL(k2_out, dim3(64 * 32), dim3(256), 0, stream,
                           query, ramps, iamps, CS, out);
    }
}

// Round 5
// 138.777 us; speedup vs baseline: 1.8965x; 1.2912x over previous
//
#include <hip/hip_runtime.h>
#include <math.h>

// Problem constants (B, SK, SQ, H, D, N) = (4, 4096, 4096, 16, 64, 32)
#define SK 4096
#define SQ 4096
#define HH 16
#define DD 64
#define NN 32

typedef __attribute__((ext_vector_type(8))) short short8;   // 8 bf16 = 4 VGPRs
typedef __attribute__((ext_vector_type(4))) float floatx4;  // MFMA C/D

// freqs[n] = (n / (N-1)) * N * pi
__device__ __forceinline__ float freq_of(int n) {
    return (float)n * (32.0f * (float)M_PI / 31.0f);
}

// fp32 -> bf16 (round to nearest even), as raw ushort
__device__ __forceinline__ unsigned short f2bf(float x) {
    unsigned u = __float_as_uint(x);
    u += 0x7FFFu + ((u >> 16) & 1u);
    return (unsigned short)(u >> 16);
}

// async global->LDS, 16 B per lane: writes lds_base + lane*16
__device__ __forceinline__ void async16(const float* g, float* l) {
    __builtin_amdgcn_global_load_lds(
        (const __attribute__((address_space(1))) unsigned int*)g,
        (__attribute__((address_space(3))) unsigned int*)l, 16, 0, 0);
}

// ---------------------------------------------------------------------------
// Kernel 1 (MFMA): partial C/S.  Per (bh, chunk): D[64 feat][64 d] over
// K = KPC keys.  feat 0-31 = cos_n, 32-63 = sin_n.  4 waves: wave w owns
// feats 16w..16w+15 x all 64 d (4 MFMA tiles), K-step = 32 keys.
// A-frag: lane feat = 16w+(l&15), keys (l>>4)*8+j  -> sincos built in-reg
// from LDS-broadcast keys (no redundancy: 4096 trig vals/batch = 1/thread/step).
// B-frag: V fp32 from DMA-staged LDS tile, cvt bf16 in-reg.
// D store: row = (l>>4)*4+reg (feat), col = l&15 (d).
// ---------------------------------------------------------------------------
template <int NC>
__global__ __launch_bounds__(256) void k1_partial(
    const float* __restrict__ key_in, const float* __restrict__ value,
    float* __restrict__ P)
{
    constexpr int KPC = SK / NC;
    constexpr int NB  = KPC / 64;          // 64-key batches
    const int chunk = blockIdx.x & (NC - 1);
    const int bh    = blockIdx.x / NC;
    const int b = bh >> 4, h = bh & 15;
    const int tid = threadIdx.x;
    const int w = tid >> 6, l = tid & 63;

    __shared__ float vt[2][64 * DD];       // 2 x 16 KB value tiles (fp32)
    __shared__ float kt[KPC];              // chunk keys

    const int k0 = chunk * KPC;

    auto issue = [&](int bb, int p) {      // 16 KB via 4 async16 per wave
        const int kb = k0 + bb * 64;
        #pragma unroll
        for (int i = 0; i < 4; ++i) {
            const float* gv = value
                + (size_t)(b * SK + kb + (w * 4 + i) * 4 + (l >> 4)) * (HH * DD)
                + h * DD + (l & 15) * 4;
            async16(gv, &vt[p][(w * 4 + i) * 256]);
        }
    };

    issue(0, 0);
    // stage all chunk keys once (strided gather, one-time)
    #pragma unroll
    for (int i = 0; i < KPC / 256; ++i)
        kt[tid + i * 256] = key_in[(size_t)(b * SK + k0 + tid + i * 256) * HH + h];

    const int fl = l & 15;                 // feat_local (A) / d_local (B,D)
    const int qd = l >> 4;                 // quad
    const int feat = w * 16 + fl;
    const float fn = freq_of(feat & 31);
    const bool use_sin = (w >= 2);

    floatx4 acc[4];
    #pragma unroll
    for (int dt = 0; dt < 4; ++dt) acc[dt] = (floatx4){0.f, 0.f, 0.f, 0.f};

    for (int bb = 0; bb < NB; ++bb) {
        const int p = bb & 1;
        __syncthreads();                   // drains DMA(bb); vt[p] ready
        if (bb + 1 < NB) issue(bb + 1, p ^ 1);

        #pragma unroll
        for (int s = 0; s < 2; ++s) {      // 2 K-steps of 32 keys
            const int kk = bb * 64 + s * 32 + qd * 8;
            float4 ka  = *(const float4*)&kt[kk];
            float4 kb4 = *(const float4*)&kt[kk + 4];
            float kj[8] = {ka.x, ka.y, ka.z, ka.w, kb4.x, kb4.y, kb4.z, kb4.w};

            union { short8 v; unsigned short u[8]; } A;
            #pragma unroll
            for (int j = 0; j < 8; ++j) {
                float ang = fn * kj[j];
                A.u[j] = f2bf(use_sin ? __sinf(ang) : __cosf(ang));
            }

            const int vb = (s * 32 + qd * 8) * DD + fl;
            #pragma unroll
            for (int dt = 0; dt < 4; ++dt) {
                union { short8 v; unsigned short u[8]; } Bf;
                #pragma unroll
                for (int j = 0; j < 8; ++j)
                    Bf.u[j] = f2bf(vt[p][vb + j * DD + dt * 16]);
                acc[dt] = __builtin_amdgcn_mfma_f32_16x16x32_bf16(
                    A.v, Bf.v, acc[dt], 0, 0, 0);
            }
        }
    }

    float* Pb = P + ((size_t)chunk * 64 + bh) * (2 * NN * DD);
    #pragma unroll
    for (int dt = 0; dt < 4; ++dt)
        #pragma unroll
        for (int r = 0; r < 4; ++r) {
            int frow = w * 16 + qd * 4 + r;          // D row = feat
            Pb[frow * DD + dt * 16 + fl] = acc[dt][r];
        }
}

// ---------------------------------------------------------------------------
// Kernel 1b: reduce the NC chunk partials.  CS[bh][feat][d] (262144 floats).
// ---------------------------------------------------------------------------
template <int NC>
__global__ __launch_bounds__(256) void k1_reduce(
    const float* __restrict__ P, float* __restrict__ CS)
{
    int gid = blockIdx.x * 256 + threadIdx.x;
    float acc = 0.f;
    #pragma unroll
    for (int c = 0; c < NC; ++c)
        acc += P[(size_t)c * (64 * 2 * NN * DD) + gid];
    CS[gid] = acc;
}

// ---------------------------------------------------------------------------
// Kernel 2 (MFMA): out[q][d] = sum_feat Aq[q][feat] * CS[feat][d], K = 64
// (feats 0-31: A_n = ra cos + ia sin vs C; 32-63: B_n = ra sin - ia cos vs S).
// Block = 64 q x 64 d; wave w owns q 16w..16w+15 x 4 d-tiles; 2 K-steps.
// CS staged in LDS as bf16 TRANSPOSED [d][feat] with 16B-block XOR swizzle
// (fb ^ (d&7)) so B-frags are single conflict-free ds_read_b128.
// A-frags: 8 sincos per lane (q = 16w+(l&15), n = (l>>4)*8+j) - no redundancy.
// ---------------------------------------------------------------------------
__global__ __launch_bounds__(256) void k2_out(
    const float* __restrict__ query, const float* __restrict__ ramps,
    const float* __restrict__ iamps, const float* __restrict__ CS,
    float* __restrict__ out)
{
    const int bh = blockIdx.x >> 6;
    const int qc = blockIdx.x & 63;
    const int b = bh >> 4, h = bh & 15;
    const int qbase = qc * 64;
    const int tid = threadIdx.x;
    const int w = tid >> 6, l = tid & 63;

    __shared__ unsigned short cst[64 * 64];   // 8 KB: bf16 CS^T, swizzled
    __shared__ float qv[64];

    // stage CS (fp32 [feat][d]) -> bf16 [d][feat] with XOR swizzle
    {
        const float* CSb = CS + (size_t)bh * (2 * NN * DD);
        const int feat = tid >> 2, dbase = (tid & 3) * 16;
        const int fb = feat >> 3, f7 = feat & 7;
        #pragma unroll
        for (int i = 0; i < 4; ++i) {
            float4 v = *(const float4*)&CSb[feat * DD + dbase + i * 4];
            float vv[4] = {v.x, v.y, v.z, v.w};
            #pragma unroll
            for (int e = 0; e < 4; ++e) {
                int d = dbase + i * 4 + e;
                cst[d * 64 + ((fb ^ (d & 7)) << 3) + f7] = f2bf(vv[e]);
            }
        }
    }
    if (tid < 64)
        qv[tid] = query[(size_t)(b * SQ + qbase + tid) * HH + h];
    __syncthreads();

    const int fl = l & 15, qd = l >> 4;
    const float qval = qv[w * 16 + fl];       // broadcast read
    const int nb = qd * 8;
    float4 raA = *(const float4*)&ramps[h * NN + nb];
    float4 raB = *(const float4*)&ramps[h * NN + nb + 4];
    float4 iaA = *(const float4*)&iamps[h * NN + nb];
    float4 iaB = *(const float4*)&iamps[h * NN + nb + 4];
    float ra[8] = {raA.x, raA.y, raA.z, raA.w, raB.x, raB.y, raB.z, raB.w};
    float ia[8] = {iaA.x, iaA.y, iaA.z, iaA.w, iaB.x, iaB.y, iaB.z, iaB.w};

    union { short8 v; unsigned short u[8]; } A0, A1;
    #pragma unroll
    for (int j = 0; j < 8; ++j) {
        float s, c;
        __sincosf(freq_of(nb + j) * qval, &s, &c);
        A0.u[j] = f2bf(ra[j] * c + ia[j] * s);   // vs C rows (feats 0-31)
        A1.u[j] = f2bf(ra[j] * s - ia[j] * c);   // vs S rows (feats 32-63)
    }

    floatx4 acc[4];
    #pragma unroll
    for (int dt = 0; dt < 4; ++dt) acc[dt] = (floatx4){0.f, 0.f, 0.f, 0.f};

    #pragma unroll
    for (int dt = 0; dt < 4; ++dt) {
        const int d = dt * 16 + fl;
        short8 B0 = *(const short8*)&cst[d * 64 + ((qd ^ (d & 7)) << 3)];
        short8 B1 = *(const short8*)&cst[d * 64 + (((4 + qd) ^ (d & 7)) << 3)];
        acc[dt] = __builtin_amdgcn_mfma_f32_16x16x32_bf16(A0.v, B0, acc[dt], 0, 0, 0);
        acc[dt] = __builtin_amdgcn_mfma_f32_16x16x32_bf16(A1.v, B1, acc[dt], 0, 0, 0);
    }

    float* ob = out + ((size_t)(b * SQ + qbase) * HH + h) * DD;
    #pragma unroll
    for (int dt = 0; dt < 4; ++dt)
        #pragma unroll
        for (int r = 0; r < 4; ++r) {
            int q = w * 16 + qd * 4 + r;          // D row = q
            ob[(size_t)q * (HH * DD) + dt * 16 + fl] = acc[dt][r];
        }
}

extern "C" void kernel_launch(void* const* d_in, const int* in_sizes, int n_in,
                              void* d_out, int out_size, void* d_ws, size_t ws_size,
                              hipStream_t stream) {
    const float* key_in = (const float*)d_in[0];
    const float* value  = (const float*)d_in[1];
    const float* query  = (const float*)d_in[2];
    const float* ramps  = (const float*)d_in[3];
    const float* iamps  = (const float*)d_in[4];
    float* out = (float*)d_out;

    const size_t CS_FLOATS  = 64 * 2 * NN * DD;            // 262144
    const size_t P16_FLOATS = (size_t)16 * CS_FLOATS;      // ~16.8 MB
    const size_t need16 = (P16_FLOATS + CS_FLOATS) * sizeof(float);

    float* P = (float*)d_ws;

    if (ws_size >= need16) {
        float* CSp = P + P16_FLOATS;
        hipLaunchKernelGGL((k1_partial<16>), dim3(64 * 16), dim3(256), 0, stream,
                           key_in, value, P);
        hipLaunchKernelGGL((k1_reduce<16>), dim3(CS_FLOATS / 256), dim3(256), 0, stream,
                           P, CSp);
        hipLaunchKernelGGL(k2_out, dim3(64 * 64), dim3(256), 0, stream,
                           query, ramps, iamps, CSp, out);
    } else {
        float* CSp = P + (size_t)8 * CS_FLOATS;
        hipLaunchKernelGGL((k1_partial<8>), dim3(64 * 8), dim3(256), 0, stream,
                           key_in, value, P);
        hipLaunchKernelGGL((k1_reduce<8>), dim3(CS_FLOATS / 256), dim3(256), 0, stream,
                           P, CSp);
        hipLaunchKernelGGL(k2_out, dim3(64 * 64), dim3(256), 0, stream,
                           query, ramps, iamps, CSp, out);
    }
}